// Round 1
// baseline (1242.380 us; speedup 1.0000x reference)
//
#include <hip/hip_runtime.h>
#include <hip/hip_bf16.h>
#include <math.h>

#define NNODES 50000
#define NEDGES 800000

// ---------------- CSR build ----------------
__global__ void count_deg_kernel(const int* __restrict__ dst, int* __restrict__ deg) {
    int e = blockIdx.x * blockDim.x + threadIdx.x;
    if (e < NEDGES) atomicAdd(&deg[dst[e]], 1);
}

__global__ void scan_kernel(const int* __restrict__ deg, int* __restrict__ row_ptr) {
    __shared__ int part[1024];
    const int C = (NNODES + 1023) / 1024;  // 49
    int t = threadIdx.x;
    int beg = t * C;
    int s = 0;
    for (int i = 0; i < C; i++) {
        int idx = beg + i;
        if (idx < NNODES) s += deg[idx];
    }
    part[t] = s;
    __syncthreads();
    for (int off = 1; off < 1024; off <<= 1) {
        int val = (t >= off) ? part[t - off] : 0;
        __syncthreads();
        part[t] += val;
        __syncthreads();
    }
    int run = (t == 0) ? 0 : part[t - 1];
    for (int i = 0; i < C; i++) {
        int idx = beg + i;
        if (idx < NNODES) { row_ptr[idx] = run; run += deg[idx]; }
    }
    if (t == 1023) row_ptr[NNODES] = run;
}

__global__ void scatter_kernel(const int* __restrict__ src, const int* __restrict__ dst,
                               const int* __restrict__ row_ptr, int* __restrict__ cursor,
                               int* __restrict__ esrc) {
    int e = blockIdx.x * blockDim.x + threadIdx.x;
    if (e >= NEDGES) return;
    int d = dst[e];
    int slot = row_ptr[d] + atomicAdd(&cursor[d], 1);
    esrc[slot] = src[e];
}

// ---------------- fused 4-matrix GEMM:  C_i = A @ W_i + b_i ----------------
struct Gemm4Args {
    const float* W[4];
    const float* b[4];
    float*       C[4];
};

#define BM 64
#define BN 64
#define BKK 32

template <int K, int NC>
__global__ void gemm4_kernel(const float* __restrict__ A, Gemm4Args args, int M) {
    __shared__ float As[BKK][BM + 4];  // +4 keeps float4 alignment
    __shared__ float Bs[BKK][BN + 4];

    int tile_r = blockIdx.x * BM;
    int tcg    = blockIdx.y * BN;        // global column in [0, 4*NC)
    int mat    = tcg / NC;
    int tile_c = tcg % NC;
    const float* W  = args.W[mat];
    const float* bb = args.b[mat];
    float*       C  = args.C[mat];

    int t  = threadIdx.x;          // 256
    int tx = t & 15, ty = t >> 4;  // 16x16
    float acc[4][4] = {};

    for (int kk = 0; kk < K; kk += BKK) {
        // A tile: 64 rows x 32 k
        #pragma unroll
        for (int i = 0; i < 8; i++) {
            int lin = t + i * 256;
            int r  = lin >> 5;
            int kx = lin & 31;
            int gr = tile_r + r;
            As[kx][r] = (gr < M) ? A[(size_t)gr * K + kk + kx] : 0.f;
        }
        // W tile: 32 k x 64 c
        #pragma unroll
        for (int i = 0; i < 8; i++) {
            int lin = t + i * 256;
            int kx = lin >> 6;
            int c  = lin & 63;
            Bs[kx][c] = W[(size_t)(kk + kx) * NC + tile_c + c];
        }
        __syncthreads();
        #pragma unroll
        for (int k = 0; k < BKK; k++) {
            float4 a4 = *(const float4*)&As[k][ty * 4];
            float4 b4 = *(const float4*)&Bs[k][tx * 4];
            float av[4] = {a4.x, a4.y, a4.z, a4.w};
            float bv[4] = {b4.x, b4.y, b4.z, b4.w};
            #pragma unroll
            for (int i = 0; i < 4; i++)
                #pragma unroll
                for (int j = 0; j < 4; j++) acc[i][j] += av[i] * bv[j];
        }
        __syncthreads();
    }
    #pragma unroll
    for (int i = 0; i < 4; i++) {
        int gr = tile_r + ty * 4 + i;
        if (gr >= M) continue;
        #pragma unroll
        for (int j = 0; j < 4; j++) {
            int gc = tile_c + tx * 4 + j;
            C[(size_t)gr * NC + gc] = acc[i][j] + bb[gc];
        }
    }
}

// ---------------- attention layer 1: heads=4, d=64; one wave per (node, head) ----------------
__global__ void attn1_kernel(const float* __restrict__ q, const float* __restrict__ k,
                             const float* __restrict__ v, const int* __restrict__ row_ptr,
                             const int* __restrict__ esrc, float* __restrict__ h) {
    int wave = blockIdx.x * 4 + (threadIdx.x >> 6);  // 4 waves per block
    int lane = threadIdx.x & 63;
    int n = wave >> 2;
    int head = wave & 3;
    int base = head * 64 + lane;

    float qj = q[(size_t)n * 256 + base];
    int beg = row_ptr[n], end = row_ptr[n + 1];

    float m = -INFINITY, l = 0.f, acc = 0.f;
    for (int i = beg; i < end; i++) {
        int s = esrc[i];
        float kj = k[(size_t)s * 256 + base];
        float vj = v[(size_t)s * 256 + base];
        float p = qj * kj;
        #pragma unroll
        for (int o = 32; o; o >>= 1) p += __shfl_xor(p, o, 64);
        float logit = p * 0.125f;  // 1/sqrt(64)
        float nm = fmaxf(m, logit);
        float f  = __expf(m - nm);     // exp(-inf)=0 on first edge
        float pe = __expf(logit - nm);
        l   = l * f + pe;
        acc = acc * f + pe * vj;
        m = nm;
    }
    float res = (l > 0.f) ? acc / l : 0.f;
    size_t o = (size_t)n * 256 + base;
    h[o] = fmaxf(h[o] + res, 0.f);  // skip + attn, then ReLU
}

// ---------------- attention layer 2: heads=1, d=128; one wave per node ----------------
__global__ void attn2_kernel(const float* __restrict__ q, const float* __restrict__ k,
                             const float* __restrict__ v, const int* __restrict__ row_ptr,
                             const int* __restrict__ esrc, float* __restrict__ h2) {
    int n = blockIdx.x * 4 + (threadIdx.x >> 6);
    int lane = threadIdx.x & 63;

    float qa = q[(size_t)n * 128 + lane];
    float qb = q[(size_t)n * 128 + 64 + lane];
    int beg = row_ptr[n], end = row_ptr[n + 1];

    float m = -INFINITY, l = 0.f, acca = 0.f, accb = 0.f;
    for (int i = beg; i < end; i++) {
        int s = esrc[i];
        float ka = k[(size_t)s * 128 + lane];
        float kb = k[(size_t)s * 128 + 64 + lane];
        float va = v[(size_t)s * 128 + lane];
        float vb = v[(size_t)s * 128 + 64 + lane];
        float p = qa * ka + qb * kb;
        #pragma unroll
        for (int o = 32; o; o >>= 1) p += __shfl_xor(p, o, 64);
        float logit = p * 0.08838834764831845f;  // 1/sqrt(128)
        float nm = fmaxf(m, logit);
        float f  = __expf(m - nm);
        float pe = __expf(logit - nm);
        l    = l * f + pe;
        acca = acca * f + pe * va;
        accb = accb * f + pe * vb;
        m = nm;
    }
    float ra = (l > 0.f) ? acca / l : 0.f;
    float rb = (l > 0.f) ? accb / l : 0.f;
    h2[(size_t)n * 128 + lane]      += ra;
    h2[(size_t)n * 128 + 64 + lane] += rb;
}

// ---------------- final column mean over nodes ----------------
__global__ void colmean_kernel(const float* __restrict__ h2, float* __restrict__ out) {
    int t = threadIdx.x;   // 256
    int c = t & 127;
    int half = t >> 7;
    float s = 0.f;
    for (int n = blockIdx.x * 2 + half; n < NNODES; n += gridDim.x * 2)
        s += h2[(size_t)n * 128 + c];
    __shared__ float red[256];
    red[t] = s;
    __syncthreads();
    if (half == 0) {
        float tot = red[c] + red[c + 128];
        atomicAdd(&out[c], tot * (1.0f / NNODES));
    }
}

extern "C" void kernel_launch(void* const* d_in, const int* in_sizes, int n_in,
                              void* d_out, int out_size, void* d_ws, size_t ws_size,
                              hipStream_t stream) {
    const float* x   = (const float*)d_in[0];
    const int*   ei  = (const int*)d_in[1];   // int32 (JAX x64 disabled): [2, E]
    const int* src = ei;
    const int* dst = ei + NEDGES;

    const float* Wq1 = (const float*)d_in[2];  const float* bq1 = (const float*)d_in[3];
    const float* Wk1 = (const float*)d_in[4];  const float* bk1 = (const float*)d_in[5];
    const float* Wv1 = (const float*)d_in[6];  const float* bv1 = (const float*)d_in[7];
    const float* Ws1 = (const float*)d_in[8];  const float* bs1 = (const float*)d_in[9];
    const float* Wq2 = (const float*)d_in[10]; const float* bq2 = (const float*)d_in[11];
    const float* Wk2 = (const float*)d_in[12]; const float* bk2 = (const float*)d_in[13];
    const float* Wv2 = (const float*)d_in[14]; const float* bv2 = (const float*)d_in[15];
    const float* Ws2 = (const float*)d_in[16]; const float* bs2 = (const float*)d_in[17];

    float* out = (float*)d_out;

    // workspace layout
    float* q1 = (float*)d_ws;                      // N*256
    float* k1 = q1 + (size_t)NNODES * 256;         // N*256
    float* v1 = k1 + (size_t)NNODES * 256;         // N*256
    float* h  = v1 + (size_t)NNODES * 256;         // N*256 (skip -> relu(skip+attn))
    // layer-2 buffers alias dead q1/k1 regions
    float* q2 = q1;                                // N*128
    float* k2 = q1 + (size_t)NNODES * 128;         // N*128
    float* v2 = k1;                                // N*128
    float* h2 = k1 + (size_t)NNODES * 128;         // N*128
    int* deg     = (int*)(h + (size_t)NNODES * 256);
    int* row_ptr = deg + NNODES;                   // N+1
    int* cursor  = row_ptr + NNODES + 1;           // N
    int* esrc    = cursor + NNODES;                // E

    // zero-init counters and output accumulator
    hipMemsetAsync(deg, 0, sizeof(int) * NNODES, stream);
    hipMemsetAsync(cursor, 0, sizeof(int) * NNODES, stream);
    hipMemsetAsync(out, 0, sizeof(float) * 128, stream);

    int blocksE = (NEDGES + 255) / 256;
    count_deg_kernel<<<blocksE, 256, 0, stream>>>(dst, deg);
    scan_kernel<<<1, 1024, 0, stream>>>(deg, row_ptr);
    scatter_kernel<<<blocksE, 256, 0, stream>>>(src, dst, row_ptr, cursor, esrc);

    int rowTiles = (NNODES + BM - 1) / BM;  // 782

    Gemm4Args a1;
    a1.W[0] = Wq1; a1.W[1] = Wk1; a1.W[2] = Wv1; a1.W[3] = Ws1;
    a1.b[0] = bq1; a1.b[1] = bk1; a1.b[2] = bv1; a1.b[3] = bs1;
    a1.C[0] = q1;  a1.C[1] = k1;  a1.C[2] = v1;  a1.C[3] = h;
    dim3 g1(rowTiles, (4 * 256) / BN);  // 782 x 16
    gemm4_kernel<128, 256><<<g1, 256, 0, stream>>>(x, a1, NNODES);

    attn1_kernel<<<NNODES, 256, 0, stream>>>(q1, k1, v1, row_ptr, esrc, h);

    Gemm4Args a2;
    a2.W[0] = Wq2; a2.W[1] = Wk2; a2.W[2] = Wv2; a2.W[3] = Ws2;
    a2.b[0] = bq2; a2.b[1] = bk2; a2.b[2] = bv2; a2.b[3] = bs2;
    a2.C[0] = q2;  a2.C[1] = k2;  a2.C[2] = v2;  a2.C[3] = h2;
    dim3 g2(rowTiles, (4 * 128) / BN);  // 782 x 8
    gemm4_kernel<256, 128><<<g2, 256, 0, stream>>>(h, a2, NNODES);

    attn2_kernel<<<NNODES / 4, 256, 0, stream>>>(q2, k2, v2, row_ptr, esrc, h2);

    colmean_kernel<<<256, 256, 0, stream>>>(h2, out);
}

// Round 2
// 887.103 us; speedup vs baseline: 1.4005x; 1.4005x over previous
//
#include <hip/hip_runtime.h>
#include <math.h>

#define NNODES 50000
#define NEDGES 800000
#define MPAD   50048   // NNODES rounded up to 128

typedef __bf16 bf16_t;
typedef __attribute__((ext_vector_type(8))) __bf16 bf16x8;
typedef __attribute__((ext_vector_type(4))) float  floatx4;

// ---------------- dtype prep ----------------
__global__ void cast_x_kernel(const float* __restrict__ x, bf16_t* __restrict__ xb) {
    int i = blockIdx.x * blockDim.x + threadIdx.x;   // over MPAD*128
    if (i >= MPAD * 128) return;
    int row = i >> 7;
    xb[i] = (row < NNODES) ? (bf16_t)x[i] : (bf16_t)0.f;
}

struct W4 { const float* W[4]; };

// Wt1: [1024][128]  (global col c -> mat=c>>8, n=c&255; Wt[c][k] = W[mat][k*256+n])
__global__ void transpose_w1_kernel(W4 w, bf16_t* __restrict__ wt) {
    int i = blockIdx.x * blockDim.x + threadIdx.x;   // 1024*128
    if (i >= 1024 * 128) return;
    int c = i >> 7, k = i & 127;
    int mat = c >> 8, n = c & 255;
    wt[i] = (bf16_t)w.W[mat][(size_t)k * 256 + n];
}

// Wt2: [512][256]
__global__ void transpose_w2_kernel(W4 w, bf16_t* __restrict__ wt) {
    int i = blockIdx.x * blockDim.x + threadIdx.x;   // 512*256
    if (i >= 512 * 256) return;
    int c = i >> 8, k = i & 255;
    int mat = c >> 7, n = c & 127;
    wt[i] = (bf16_t)w.W[mat][(size_t)k * 128 + n];
}

// ---------------- CSR build ----------------
__global__ void count_deg_kernel(const int* __restrict__ dst, int* __restrict__ deg) {
    int e = blockIdx.x * blockDim.x + threadIdx.x;
    if (e < NEDGES) atomicAdd(&deg[dst[e]], 1);
}

__global__ void scan_kernel(const int* __restrict__ deg, int* __restrict__ row_ptr) {
    __shared__ int part[1024];
    const int C = (NNODES + 1023) / 1024;  // 49
    int t = threadIdx.x;
    int beg = t * C;
    int s = 0;
    for (int i = 0; i < C; i++) {
        int idx = beg + i;
        if (idx < NNODES) s += deg[idx];
    }
    part[t] = s;
    __syncthreads();
    for (int off = 1; off < 1024; off <<= 1) {
        int val = (t >= off) ? part[t - off] : 0;
        __syncthreads();
        part[t] += val;
        __syncthreads();
    }
    int run = (t == 0) ? 0 : part[t - 1];
    for (int i = 0; i < C; i++) {
        int idx = beg + i;
        if (idx < NNODES) { row_ptr[idx] = run; run += deg[idx]; }
    }
    if (t == 1023) row_ptr[NNODES] = run;
}

__global__ void scatter_kernel(const int* __restrict__ src, const int* __restrict__ dst,
                               const int* __restrict__ row_ptr, int* __restrict__ cursor,
                               int* __restrict__ esrc) {
    int e = blockIdx.x * blockDim.x + threadIdx.x;
    if (e >= NEDGES) return;
    int d = dst[e];
    int slot = row_ptr[d] + atomicAdd(&cursor[d], 1);
    esrc[slot] = src[e];
}

// ---------------- bf16 MFMA GEMM: C_mat = A @ W_mat + b_mat ----------------
// A: [MPAD][K] bf16 (zero-padded rows). Wt: [4*NC][K] bf16 (pre-transposed).
// Block tile 128x128, 4 waves in 2x2, each wave 64x64 via 4x4 mfma_16x16x32 tiles.
struct GemmOut {
    const float* bias[4];
    bf16_t*      out_bf[4];   // null -> use out_f
    float*       out_f[4];
};

template <int K, int NC>
__global__ __launch_bounds__(256) void gemm_mfma_kernel(const bf16_t* __restrict__ A,
                                                        const bf16_t* __restrict__ Wt,
                                                        GemmOut args) {
    __shared__ bf16_t As[128][40];   // row stride 80 B (16B-aligned for b128)
    __shared__ bf16_t Bs[128][40];

    int t    = threadIdx.x;
    int lane = t & 63;
    int w    = t >> 6;
    int wm   = w >> 1, wn = w & 1;
    int tile_r = blockIdx.x * 128;
    int tile_c = blockIdx.y * 128;
    int mat = tile_c / NC;
    int tcl = tile_c % NC;

    floatx4 acc[4][4] = {};

    for (int kk = 0; kk < K; kk += 32) {
        #pragma unroll
        for (int i = 0; i < 2; i++) {
            int lin = t + i * 256;           // 0..511
            int row = lin >> 2;              // 0..127
            int kq  = (lin & 3) * 8;         // 0,8,16,24
            *(int4*)&As[row][kq] = *(const int4*)&A[(size_t)(tile_r + row) * K + kk + kq];
            *(int4*)&Bs[row][kq] = *(const int4*)&Wt[(size_t)(tile_c + row) * K + kk + kq];
        }
        __syncthreads();
        bf16x8 af[4], bfr[4];
        int kq = (lane >> 4) * 8;
        #pragma unroll
        for (int mi = 0; mi < 4; mi++)
            af[mi] = *(const bf16x8*)&As[wm * 64 + mi * 16 + (lane & 15)][kq];
        #pragma unroll
        for (int ni = 0; ni < 4; ni++)
            bfr[ni] = *(const bf16x8*)&Bs[wn * 64 + ni * 16 + (lane & 15)][kq];
        #pragma unroll
        for (int mi = 0; mi < 4; mi++)
            #pragma unroll
            for (int ni = 0; ni < 4; ni++)
                acc[mi][ni] = __builtin_amdgcn_mfma_f32_16x16x32_bf16(af[mi], bfr[ni], acc[mi][ni], 0, 0, 0);
        __syncthreads();
    }

    // epilogue: C/D layout col=lane&15, row=(lane>>4)*4+reg
    const float* bias = args.bias[mat];
    bf16_t* obf = args.out_bf[mat];
    float*  of  = args.out_f[mat];
    float bv[4];
    #pragma unroll
    for (int ni = 0; ni < 4; ni++) bv[ni] = bias[tcl + wn * 64 + ni * 16 + (lane & 15)];
    #pragma unroll
    for (int mi = 0; mi < 4; mi++) {
        int r0 = tile_r + wm * 64 + mi * 16 + (lane >> 4) * 4;
        #pragma unroll
        for (int r = 0; r < 4; r++) {
            int gr = r0 + r;
            if (gr >= NNODES) continue;
            #pragma unroll
            for (int ni = 0; ni < 4; ni++) {
                int oc = tcl + wn * 64 + ni * 16 + (lane & 15);
                float val = acc[mi][ni][r] + bv[ni];
                if (obf) obf[(size_t)gr * NC + oc] = (bf16_t)val;
                else     of [(size_t)gr * NC + oc] = val;
            }
        }
    }
}

// ---------------- attention layer 1: heads=4, d=64; one wave per (node, head) ----------------
__global__ void attn1_kernel(const bf16_t* __restrict__ q, const bf16_t* __restrict__ k,
                             const bf16_t* __restrict__ v, const float* __restrict__ skip,
                             const int* __restrict__ row_ptr, const int* __restrict__ esrc,
                             bf16_t* __restrict__ hout) {
    int wave = blockIdx.x * 4 + (threadIdx.x >> 6);
    int lane = threadIdx.x & 63;
    int n = wave >> 2;
    int head = wave & 3;
    int base = head * 64 + lane;

    float qj = (float)q[(size_t)n * 256 + base];
    int beg = row_ptr[n], end = row_ptr[n + 1];

    float m = -INFINITY, l = 0.f, acc = 0.f;
    for (int i = beg; i < end; i++) {
        int s = esrc[i];
        float kj = (float)k[(size_t)s * 256 + base];
        float vj = (float)v[(size_t)s * 256 + base];
        float p = qj * kj;
        #pragma unroll
        for (int o = 32; o; o >>= 1) p += __shfl_xor(p, o, 64);
        float logit = p * 0.125f;  // 1/sqrt(64)
        float nm = fmaxf(m, logit);
        float f  = __expf(m - nm);
        float pe = __expf(logit - nm);
        l   = l * f + pe;
        acc = acc * f + pe * vj;
        m = nm;
    }
    float res = (l > 0.f) ? acc / l : 0.f;
    size_t o = (size_t)n * 256 + base;
    hout[o] = (bf16_t)fmaxf(skip[o] + res, 0.f);  // skip + attn, ReLU, bf16 for GEMM2
}

// ---------------- attention layer 2: heads=1, d=128; one wave per node ----------------
__global__ void attn2_kernel(const bf16_t* __restrict__ q, const bf16_t* __restrict__ k,
                             const bf16_t* __restrict__ v, const int* __restrict__ row_ptr,
                             const int* __restrict__ esrc, float* __restrict__ h2) {
    int n = blockIdx.x * 4 + (threadIdx.x >> 6);
    int lane = threadIdx.x & 63;

    float qa = (float)q[(size_t)n * 128 + lane];
    float qb = (float)q[(size_t)n * 128 + 64 + lane];
    int beg = row_ptr[n], end = row_ptr[n + 1];

    float m = -INFINITY, l = 0.f, acca = 0.f, accb = 0.f;
    for (int i = beg; i < end; i++) {
        int s = esrc[i];
        float ka = (float)k[(size_t)s * 128 + lane];
        float kb = (float)k[(size_t)s * 128 + 64 + lane];
        float va = (float)v[(size_t)s * 128 + lane];
        float vb = (float)v[(size_t)s * 128 + 64 + lane];
        float p = qa * ka + qb * kb;
        #pragma unroll
        for (int o = 32; o; o >>= 1) p += __shfl_xor(p, o, 64);
        float logit = p * 0.08838834764831845f;  // 1/sqrt(128)
        float nm = fmaxf(m, logit);
        float f  = __expf(m - nm);
        float pe = __expf(logit - nm);
        l    = l * f + pe;
        acca = acca * f + pe * va;
        accb = accb * f + pe * vb;
        m = nm;
    }
    float ra = (l > 0.f) ? acca / l : 0.f;
    float rb = (l > 0.f) ? accb / l : 0.f;
    h2[(size_t)n * 128 + lane]      += ra;
    h2[(size_t)n * 128 + 64 + lane] += rb;
}

// ---------------- final column mean over nodes ----------------
__global__ void colmean_kernel(const float* __restrict__ h2, float* __restrict__ out) {
    int t = threadIdx.x;   // 256
    int c = t & 127;
    int half = t >> 7;
    float s = 0.f;
    for (int n = blockIdx.x * 2 + half; n < NNODES; n += gridDim.x * 2)
        s += h2[(size_t)n * 128 + c];
    __shared__ float red[256];
    red[t] = s;
    __syncthreads();
    if (half == 0) {
        float tot = red[c] + red[c + 128];
        atomicAdd(&out[c], tot * (1.0f / NNODES));
    }
}

extern "C" void kernel_launch(void* const* d_in, const int* in_sizes, int n_in,
                              void* d_out, int out_size, void* d_ws, size_t ws_size,
                              hipStream_t stream) {
    const float* x  = (const float*)d_in[0];
    const int*   ei = (const int*)d_in[1];   // int32: [2, E]
    const int* src = ei;
    const int* dst = ei + NEDGES;

    const float* Wq1 = (const float*)d_in[2];  const float* bq1 = (const float*)d_in[3];
    const float* Wk1 = (const float*)d_in[4];  const float* bk1 = (const float*)d_in[5];
    const float* Wv1 = (const float*)d_in[6];  const float* bv1 = (const float*)d_in[7];
    const float* Ws1 = (const float*)d_in[8];  const float* bs1 = (const float*)d_in[9];
    const float* Wq2 = (const float*)d_in[10]; const float* bq2 = (const float*)d_in[11];
    const float* Wk2 = (const float*)d_in[12]; const float* bk2 = (const float*)d_in[13];
    const float* Wv2 = (const float*)d_in[14]; const float* bv2 = (const float*)d_in[15];
    const float* Ws2 = (const float*)d_in[16]; const float* bs2 = (const float*)d_in[17];

    float* out = (float*)d_out;

    // ---- workspace layout (byte offsets, all 16B-aligned) ----
    char* ws = (char*)d_ws;
    bf16_t* qkv1  = (bf16_t*)(ws);                 // 3*N*256 bf16 = 76,800,000 B
    bf16_t* q1 = qkv1;
    bf16_t* k1 = qkv1 + (size_t)NNODES * 256;
    bf16_t* v1 = qkv1 + (size_t)2 * NNODES * 256;
    float*  hskip = (float*)(ws + 76800000);       // N*256 f32 = 51,200,000 B
    bf16_t* hbf   = (bf16_t*)(ws + 128000000);     // MPAD*256 bf16 = 25,624,576 B
    bf16_t* xbf   = (bf16_t*)(ws + 153624576);     // MPAD*128 bf16 = 12,812,288 B
    bf16_t* wt1   = (bf16_t*)(ws + 166436864);     // 1024*128 bf16 = 262,144 B
    bf16_t* wt2   = (bf16_t*)(ws + 166699008);     // 512*256 bf16  = 262,144 B
    int* deg     = (int*)(ws + 166961152);         // N
    int* row_ptr = deg + NNODES;                   // N+1
    int* cursor  = row_ptr + NNODES + 1;           // N
    int* esrc    = cursor + NNODES;                // E
    // layer-2 buffers alias dead qkv1 region (attn1 completes first; stream-ordered)
    bf16_t* qkv2 = (bf16_t*)(ws);                  // 3*N*128 bf16 = 38,400,000 B
    bf16_t* q2 = qkv2;
    bf16_t* k2 = qkv2 + (size_t)NNODES * 128;
    bf16_t* v2 = qkv2 + (size_t)2 * NNODES * 128;
    float*  h2 = (float*)(ws + 38400000);          // N*128 f32 = 25,600,000 B

    hipMemsetAsync(deg, 0, sizeof(int) * NNODES, stream);
    hipMemsetAsync(cursor, 0, sizeof(int) * NNODES, stream);
    hipMemsetAsync(out, 0, sizeof(float) * 128, stream);
    // zero hbf pad rows (GEMM2 A-tile loads them)
    hipMemsetAsync(hbf + (size_t)NNODES * 256, 0, (size_t)(MPAD - NNODES) * 256 * sizeof(bf16_t), stream);

    // dtype prep
    cast_x_kernel<<<(MPAD * 128 + 255) / 256, 256, 0, stream>>>(x, xbf);
    W4 w1; w1.W[0] = Wq1; w1.W[1] = Wk1; w1.W[2] = Wv1; w1.W[3] = Ws1;
    transpose_w1_kernel<<<(1024 * 128 + 255) / 256, 256, 0, stream>>>(w1, wt1);
    W4 w2; w2.W[0] = Wq2; w2.W[1] = Wk2; w2.W[2] = Wv2; w2.W[3] = Ws2;
    transpose_w2_kernel<<<(512 * 256 + 255) / 256, 256, 0, stream>>>(w2, wt2);

    // CSR
    int blocksE = (NEDGES + 255) / 256;
    count_deg_kernel<<<blocksE, 256, 0, stream>>>(dst, deg);
    scan_kernel<<<1, 1024, 0, stream>>>(deg, row_ptr);
    scatter_kernel<<<blocksE, 256, 0, stream>>>(src, dst, row_ptr, cursor, esrc);

    // layer 1
    GemmOut a1;
    a1.bias[0] = bq1; a1.bias[1] = bk1; a1.bias[2] = bv1; a1.bias[3] = bs1;
    a1.out_bf[0] = q1; a1.out_bf[1] = k1; a1.out_bf[2] = v1; a1.out_bf[3] = nullptr;
    a1.out_f[0] = nullptr; a1.out_f[1] = nullptr; a1.out_f[2] = nullptr; a1.out_f[3] = hskip;
    dim3 g1(MPAD / 128, 1024 / 128);   // 391 x 8
    gemm_mfma_kernel<128, 256><<<g1, 256, 0, stream>>>(xbf, wt1, a1);

    attn1_kernel<<<NNODES, 256, 0, stream>>>(q1, k1, v1, hskip, row_ptr, esrc, hbf);

    // layer 2
    GemmOut a2;
    a2.bias[0] = bq2; a2.bias[1] = bk2; a2.bias[2] = bv2; a2.bias[3] = bs2;
    a2.out_bf[0] = q2; a2.out_bf[1] = k2; a2.out_bf[2] = v2; a2.out_bf[3] = nullptr;
    a2.out_f[0] = nullptr; a2.out_f[1] = nullptr; a2.out_f[2] = nullptr; a2.out_f[3] = h2;
    dim3 g2(MPAD / 128, 512 / 128);    // 391 x 4
    gemm_mfma_kernel<256, 128><<<g2, 256, 0, stream>>>(hbf, wt2, a2);

    attn2_kernel<<<NNODES / 4, 256, 0, stream>>>(q2, k2, v2, row_ptr, esrc, h2);

    colmean_kernel<<<256, 256, 0, stream>>>(h2, out);
}

// Round 3
// 626.712 us; speedup vs baseline: 1.9824x; 1.4155x over previous
//
#include <hip/hip_runtime.h>
#include <math.h>

#define NNODES 50000
#define NEDGES 800000
#define MPAD   50048   // NNODES rounded up to 128

typedef __bf16 bf16_t;
typedef __attribute__((ext_vector_type(8))) __bf16 bf16x8;
typedef __attribute__((ext_vector_type(4))) float  floatx4;

__device__ __forceinline__ float bf_lo(unsigned u) { return __uint_as_float(u << 16); }
__device__ __forceinline__ float bf_hi(unsigned u) { return __uint_as_float(u & 0xffff0000u); }

// ---------------- dtype prep ----------------
__global__ void cast_x_kernel(const float* __restrict__ x, bf16_t* __restrict__ xb) {
    int i = blockIdx.x * blockDim.x + threadIdx.x;   // over MPAD*128
    if (i >= MPAD * 128) return;
    int row = i >> 7;
    xb[i] = (row < NNODES) ? (bf16_t)x[i] : (bf16_t)0.f;
}

struct W4 { const float* W[4]; };

// Wt1: [1024][128]  (global col c -> mat=c>>8, n=c&255; Wt[c][k] = W[mat][k*256+n])
__global__ void transpose_w1_kernel(W4 w, bf16_t* __restrict__ wt) {
    int i = blockIdx.x * blockDim.x + threadIdx.x;   // 1024*128
    if (i >= 1024 * 128) return;
    int c = i >> 7, k = i & 127;
    int mat = c >> 8, n = c & 255;
    wt[i] = (bf16_t)w.W[mat][(size_t)k * 256 + n];
}

// Wt2: [512][256]
__global__ void transpose_w2_kernel(W4 w, bf16_t* __restrict__ wt) {
    int i = blockIdx.x * blockDim.x + threadIdx.x;   // 512*256
    if (i >= 512 * 256) return;
    int c = i >> 8, k = i & 255;
    int mat = c >> 7, n = c & 127;
    wt[i] = (bf16_t)w.W[mat][(size_t)k * 128 + n];
}

// ---------------- CSR build ----------------
__global__ void count_deg_kernel(const int* __restrict__ dst, int* __restrict__ deg) {
    int e = blockIdx.x * blockDim.x + threadIdx.x;
    if (e < NEDGES) atomicAdd(&deg[dst[e]], 1);
}

__global__ void scan_kernel(const int* __restrict__ deg, int* __restrict__ row_ptr) {
    __shared__ int part[1024];
    const int C = (NNODES + 1023) / 1024;  // 49
    int t = threadIdx.x;
    int beg = t * C;
    int s = 0;
    for (int i = 0; i < C; i++) {
        int idx = beg + i;
        if (idx < NNODES) s += deg[idx];
    }
    part[t] = s;
    __syncthreads();
    for (int off = 1; off < 1024; off <<= 1) {
        int val = (t >= off) ? part[t - off] : 0;
        __syncthreads();
        part[t] += val;
        __syncthreads();
    }
    int run = (t == 0) ? 0 : part[t - 1];
    for (int i = 0; i < C; i++) {
        int idx = beg + i;
        if (idx < NNODES) { row_ptr[idx] = run; run += deg[idx]; }
    }
    if (t == 1023) row_ptr[NNODES] = run;
}

__global__ void scatter_kernel(const int* __restrict__ src, const int* __restrict__ dst,
                               const int* __restrict__ row_ptr, int* __restrict__ cursor,
                               int* __restrict__ esrc) {
    int e = blockIdx.x * blockDim.x + threadIdx.x;
    if (e >= NEDGES) return;
    int d = dst[e];
    int slot = row_ptr[d] + atomicAdd(&cursor[d], 1);
    esrc[slot] = src[e];
}

// ---------------- bf16 MFMA GEMM: C_mat = A @ W_mat + b_mat ----------------
struct GemmOut {
    const float* bias[4];
    bf16_t*      out_bf[4];   // null -> use out_f
    float*       out_f[4];
};

template <int K, int NC>
__global__ __launch_bounds__(256) void gemm_mfma_kernel(const bf16_t* __restrict__ A,
                                                        const bf16_t* __restrict__ Wt,
                                                        GemmOut args) {
    __shared__ bf16_t As[128][40];   // row stride 80 B (16B-aligned for b128)
    __shared__ bf16_t Bs[128][40];

    int t    = threadIdx.x;
    int lane = t & 63;
    int w    = t >> 6;
    int wm   = w >> 1, wn = w & 1;
    int tile_r = blockIdx.x * 128;
    int tile_c = blockIdx.y * 128;
    int mat = tile_c / NC;
    int tcl = tile_c % NC;

    floatx4 acc[4][4] = {};

    for (int kk = 0; kk < K; kk += 32) {
        #pragma unroll
        for (int i = 0; i < 2; i++) {
            int lin = t + i * 256;           // 0..511
            int row = lin >> 2;              // 0..127
            int kq  = (lin & 3) * 8;         // 0,8,16,24
            *(int4*)&As[row][kq] = *(const int4*)&A[(size_t)(tile_r + row) * K + kk + kq];
            *(int4*)&Bs[row][kq] = *(const int4*)&Wt[(size_t)(tile_c + row) * K + kk + kq];
        }
        __syncthreads();
        bf16x8 af[4], bfr[4];
        int kq = (lane >> 4) * 8;
        #pragma unroll
        for (int mi = 0; mi < 4; mi++)
            af[mi] = *(const bf16x8*)&As[wm * 64 + mi * 16 + (lane & 15)][kq];
        #pragma unroll
        for (int ni = 0; ni < 4; ni++)
            bfr[ni] = *(const bf16x8*)&Bs[wn * 64 + ni * 16 + (lane & 15)][kq];
        #pragma unroll
        for (int mi = 0; mi < 4; mi++)
            #pragma unroll
            for (int ni = 0; ni < 4; ni++)
                acc[mi][ni] = __builtin_amdgcn_mfma_f32_16x16x32_bf16(af[mi], bfr[ni], acc[mi][ni], 0, 0, 0);
        __syncthreads();
    }

    // epilogue: C/D layout col=lane&15, row=(lane>>4)*4+reg
    const float* bias = args.bias[mat];
    bf16_t* obf = args.out_bf[mat];
    float*  of  = args.out_f[mat];
    float bv[4];
    #pragma unroll
    for (int ni = 0; ni < 4; ni++) bv[ni] = bias[tcl + wn * 64 + ni * 16 + (lane & 15)];
    #pragma unroll
    for (int mi = 0; mi < 4; mi++) {
        int r0 = tile_r + wm * 64 + mi * 16 + (lane >> 4) * 4;
        #pragma unroll
        for (int r = 0; r < 4; r++) {
            int gr = r0 + r;
            if (gr >= NNODES) continue;
            #pragma unroll
            for (int ni = 0; ni < 4; ni++) {
                int oc = tcl + wn * 64 + ni * 16 + (lane & 15);
                float val = acc[mi][ni][r] + bv[ni];
                if (obf) obf[(size_t)gr * NC + oc] = (bf16_t)val;
                else     of [(size_t)gr * NC + oc] = val;
            }
        }
    }
}

// ---------------- attention layer 1: heads=4, d=64; ONE WAVE PER NODE (all 4 heads) ----
// lane = head*16 + sub; lane covers dims [lane*4, lane*4+4) of the 256-wide row.
__global__ void attn1_kernel(const bf16_t* __restrict__ q, const bf16_t* __restrict__ k,
                             const bf16_t* __restrict__ v, const float* __restrict__ skip,
                             const int* __restrict__ row_ptr, const int* __restrict__ esrc,
                             bf16_t* __restrict__ hout) {
    int n = blockIdx.x * 4 + (threadIdx.x >> 6);
    int lane = threadIdx.x & 63;
    int off = lane * 4;   // dim offset within 256

    const uint2* qp = (const uint2*)(q + (size_t)n * 256 + off);
    uint2 qu = *qp;
    float q0 = bf_lo(qu.x), q1 = bf_hi(qu.x), q2 = bf_lo(qu.y), q3 = bf_hi(qu.y);

    int beg = row_ptr[n], end = row_ptr[n + 1];

    float m = -INFINITY, l = 0.f;
    float a0 = 0.f, a1 = 0.f, a2 = 0.f, a3 = 0.f;

    // software pipeline: prefetch edge i+1 while processing edge i
    int s_cur = (beg < end) ? esrc[beg] : 0;
    uint2 ku = (beg < end) ? *(const uint2*)(k + (size_t)s_cur * 256 + off) : make_uint2(0, 0);
    uint2 vu = (beg < end) ? *(const uint2*)(v + (size_t)s_cur * 256 + off) : make_uint2(0, 0);

    for (int i = beg; i < end; i++) {
        int s_nxt = (i + 1 < end) ? esrc[i + 1] : 0;
        uint2 kn = *(const uint2*)(k + (size_t)s_nxt * 256 + off);
        uint2 vn = *(const uint2*)(v + (size_t)s_nxt * 256 + off);

        float p = q0 * bf_lo(ku.x) + q1 * bf_hi(ku.x) + q2 * bf_lo(ku.y) + q3 * bf_hi(ku.y);
        // reduce across the 16 lanes of this head group
        p += __shfl_xor(p, 1, 64);
        p += __shfl_xor(p, 2, 64);
        p += __shfl_xor(p, 4, 64);
        p += __shfl_xor(p, 8, 64);
        float logit = p * 0.125f;  // 1/sqrt(64)
        float nm = fmaxf(m, logit);
        float f  = __expf(m - nm);
        float pe = __expf(logit - nm);
        l = l * f + pe;
        a0 = a0 * f + pe * bf_lo(vu.x);
        a1 = a1 * f + pe * bf_hi(vu.x);
        a2 = a2 * f + pe * bf_lo(vu.y);
        a3 = a3 * f + pe * bf_hi(vu.y);
        m = nm;
        ku = kn; vu = vn;
    }
    float inv = (l > 0.f) ? 1.f / l : 0.f;
    size_t o = (size_t)n * 256 + off;
    bf16_t r[4];
    r[0] = (bf16_t)fmaxf(skip[o + 0] + a0 * inv, 0.f);
    r[1] = (bf16_t)fmaxf(skip[o + 1] + a1 * inv, 0.f);
    r[2] = (bf16_t)fmaxf(skip[o + 2] + a2 * inv, 0.f);
    r[3] = (bf16_t)fmaxf(skip[o + 3] + a3 * inv, 0.f);
    *(uint2*)(hout + o) = *(uint2*)r;
}

// ---------------- attention layer 2: heads=1, d=128; one wave per node ----------------
// lane covers dims [lane*2, lane*2+2)
__global__ void attn2_kernel(const bf16_t* __restrict__ q, const bf16_t* __restrict__ k,
                             const bf16_t* __restrict__ v, const int* __restrict__ row_ptr,
                             const int* __restrict__ esrc, float* __restrict__ h2) {
    int n = blockIdx.x * 4 + (threadIdx.x >> 6);
    int lane = threadIdx.x & 63;
    int off = lane * 2;

    unsigned qu = *(const unsigned*)(q + (size_t)n * 128 + off);
    float q0 = bf_lo(qu), q1 = bf_hi(qu);

    int beg = row_ptr[n], end = row_ptr[n + 1];

    float m = -INFINITY, l = 0.f, a0 = 0.f, a1 = 0.f;

    int s_cur = (beg < end) ? esrc[beg] : 0;
    unsigned ku = (beg < end) ? *(const unsigned*)(k + (size_t)s_cur * 128 + off) : 0u;
    unsigned vu = (beg < end) ? *(const unsigned*)(v + (size_t)s_cur * 128 + off) : 0u;

    for (int i = beg; i < end; i++) {
        int s_nxt = (i + 1 < end) ? esrc[i + 1] : 0;
        unsigned kn = *(const unsigned*)(k + (size_t)s_nxt * 128 + off);
        unsigned vn = *(const unsigned*)(v + (size_t)s_nxt * 128 + off);

        float p = q0 * bf_lo(ku) + q1 * bf_hi(ku);
        #pragma unroll
        for (int o = 32; o; o >>= 1) p += __shfl_xor(p, o, 64);
        float logit = p * 0.08838834764831845f;  // 1/sqrt(128)
        float nm = fmaxf(m, logit);
        float f  = __expf(m - nm);
        float pe = __expf(logit - nm);
        l  = l * f + pe;
        a0 = a0 * f + pe * bf_lo(vu);
        a1 = a1 * f + pe * bf_hi(vu);
        m = nm;
        ku = kn; vu = vn;
    }
    float inv = (l > 0.f) ? 1.f / l : 0.f;
    float2* p2 = (float2*)(h2 + (size_t)n * 128 + off);
    float2 cur = *p2;
    cur.x += a0 * inv;
    cur.y += a1 * inv;
    *p2 = cur;
}

// ---------------- final column mean over nodes ----------------
__global__ void colmean_kernel(const float* __restrict__ h2, float* __restrict__ out) {
    int t = threadIdx.x;   // 256
    int c = t & 127;
    int half = t >> 7;
    float s = 0.f;
    for (int n = blockIdx.x * 2 + half; n < NNODES; n += gridDim.x * 2)
        s += h2[(size_t)n * 128 + c];
    __shared__ float red[256];
    red[t] = s;
    __syncthreads();
    if (half == 0) {
        float tot = red[c] + red[c + 128];
        atomicAdd(&out[c], tot * (1.0f / NNODES));
    }
}

extern "C" void kernel_launch(void* const* d_in, const int* in_sizes, int n_in,
                              void* d_out, int out_size, void* d_ws, size_t ws_size,
                              hipStream_t stream) {
    const float* x  = (const float*)d_in[0];
    const int*   ei = (const int*)d_in[1];   // int32: [2, E]
    const int* src = ei;
    const int* dst = ei + NEDGES;

    const float* Wq1 = (const float*)d_in[2];  const float* bq1 = (const float*)d_in[3];
    const float* Wk1 = (const float*)d_in[4];  const float* bk1 = (const float*)d_in[5];
    const float* Wv1 = (const float*)d_in[6];  const float* bv1 = (const float*)d_in[7];
    const float* Ws1 = (const float*)d_in[8];  const float* bs1 = (const float*)d_in[9];
    const float* Wq2 = (const float*)d_in[10]; const float* bq2 = (const float*)d_in[11];
    const float* Wk2 = (const float*)d_in[12]; const float* bk2 = (const float*)d_in[13];
    const float* Wv2 = (const float*)d_in[14]; const float* bv2 = (const float*)d_in[15];
    const float* Ws2 = (const float*)d_in[16]; const float* bs2 = (const float*)d_in[17];

    float* out = (float*)d_out;

    // ---- workspace layout (byte offsets, all 16B-aligned) ----
    char* ws = (char*)d_ws;
    bf16_t* qkv1  = (bf16_t*)(ws);                 // 3*N*256 bf16 = 76,800,000 B
    bf16_t* q1 = qkv1;
    bf16_t* k1 = qkv1 + (size_t)NNODES * 256;
    bf16_t* v1 = qkv1 + (size_t)2 * NNODES * 256;
    float*  hskip = (float*)(ws + 76800000);       // N*256 f32 = 51,200,000 B
    bf16_t* hbf   = (bf16_t*)(ws + 128000000);     // MPAD*256 bf16 = 25,624,576 B
    bf16_t* xbf   = (bf16_t*)(ws + 153624576);     // MPAD*128 bf16 = 12,812,288 B
    bf16_t* wt1   = (bf16_t*)(ws + 166436864);     // 1024*128 bf16 = 262,144 B
    bf16_t* wt2   = (bf16_t*)(ws + 166699008);     // 512*256 bf16  = 262,144 B
    int* deg     = (int*)(ws + 166961152);         // N
    int* row_ptr = deg + NNODES;                   // N+1
    int* cursor  = row_ptr + NNODES + 1;           // N
    int* esrc    = cursor + NNODES;                // E
    // layer-2 buffers alias dead qkv1 region (attn1 completes first; stream-ordered)
    bf16_t* qkv2 = (bf16_t*)(ws);                  // 3*N*128 bf16 = 38,400,000 B
    bf16_t* q2 = qkv2;
    bf16_t* k2 = qkv2 + (size_t)NNODES * 128;
    bf16_t* v2 = qkv2 + (size_t)2 * NNODES * 128;
    float*  h2 = (float*)(ws + 38400000);          // N*128 f32 = 25,600,000 B

    hipMemsetAsync(deg, 0, sizeof(int) * NNODES, stream);
    hipMemsetAsync(cursor, 0, sizeof(int) * NNODES, stream);
    hipMemsetAsync(out, 0, sizeof(float) * 128, stream);
    hipMemsetAsync(hbf + (size_t)NNODES * 256, 0, (size_t)(MPAD - NNODES) * 256 * sizeof(bf16_t), stream);

    // dtype prep
    cast_x_kernel<<<(MPAD * 128 + 255) / 256, 256, 0, stream>>>(x, xbf);
    W4 w1; w1.W[0] = Wq1; w1.W[1] = Wk1; w1.W[2] = Wv1; w1.W[3] = Ws1;
    transpose_w1_kernel<<<(1024 * 128 + 255) / 256, 256, 0, stream>>>(w1, wt1);
    W4 w2; w2.W[0] = Wq2; w2.W[1] = Wk2; w2.W[2] = Wv2; w2.W[3] = Ws2;
    transpose_w2_kernel<<<(512 * 256 + 255) / 256, 256, 0, stream>>>(w2, wt2);

    // CSR
    int blocksE = (NEDGES + 255) / 256;
    count_deg_kernel<<<blocksE, 256, 0, stream>>>(dst, deg);
    scan_kernel<<<1, 1024, 0, stream>>>(deg, row_ptr);
    scatter_kernel<<<blocksE, 256, 0, stream>>>(src, dst, row_ptr, cursor, esrc);

    // layer 1
    GemmOut a1;
    a1.bias[0] = bq1; a1.bias[1] = bk1; a1.bias[2] = bv1; a1.bias[3] = bs1;
    a1.out_bf[0] = q1; a1.out_bf[1] = k1; a1.out_bf[2] = v1; a1.out_bf[3] = nullptr;
    a1.out_f[0] = nullptr; a1.out_f[1] = nullptr; a1.out_f[2] = nullptr; a1.out_f[3] = hskip;
    dim3 g1(MPAD / 128, 1024 / 128);   // 391 x 8
    gemm_mfma_kernel<128, 256><<<g1, 256, 0, stream>>>(xbf, wt1, a1);

    attn1_kernel<<<NNODES / 4, 256, 0, stream>>>(q1, k1, v1, hskip, row_ptr, esrc, hbf);

    // layer 2
    GemmOut a2;
    a2.bias[0] = bq2; a2.bias[1] = bk2; a2.bias[2] = bv2; a2.bias[3] = bs2;
    a2.out_bf[0] = q2; a2.out_bf[1] = k2; a2.out_bf[2] = v2; a2.out_bf[3] = nullptr;
    a2.out_f[0] = nullptr; a2.out_f[1] = nullptr; a2.out_f[2] = nullptr; a2.out_f[3] = h2;
    dim3 g2(MPAD / 128, 512 / 128);    // 391 x 4
    gemm_mfma_kernel<256, 128><<<g2, 256, 0, stream>>>(hbf, wt2, a2);

    attn2_kernel<<<NNODES / 4, 256, 0, stream>>>(q2, k2, v2, row_ptr, esrc, h2);

    colmean_kernel<<<256, 256, 0, stream>>>(h2, out);
}